// Round 1
// baseline (349.727 us; speedup 1.0000x reference)
//
#include <hip/hip_runtime.h>

#define EPSF 1e-6f

constexpr int B = 128, L = 512, S = 512, C = 64;
constexpr int TILE_R = 128;           // rows per pass-1 block
constexpr int TILES  = L / TILE_R;    // 4
constexpr int CHUNK  = 128;           // cols per k-chunk
constexpr int NCHUNK = S / CHUNK;     // 4
constexpr int LSTR   = 132;           // padded LDS stride (16B-aligned float4 reads)

// workspace float offsets
constexpr size_t WS_COLMAX = 0;
constexpr size_t WS_COLSUM = WS_COLMAX + (size_t)B * TILES * S;
constexpr size_t WS_COLSSQ = WS_COLSUM + (size_t)B * TILES * S;
constexpr size_t WS_COLP1  = WS_COLSSQ + (size_t)B * TILES * S;
constexpr size_t WS_ROWMAX = WS_COLP1  + (size_t)B * TILES * S;
constexpr size_t WS_ROWSUM = WS_ROWMAX + (size_t)B * L;
constexpr size_t WS_ROWSSQ = WS_ROWSUM + (size_t)B * L;
constexpr size_t WS_ROWP2  = WS_ROWSSQ + (size_t)B * L;
constexpr size_t WS_NEGS   = WS_ROWP2  + (size_t)B * L;
constexpr size_t WS_NEGC   = WS_NEGS   + (size_t)B * TILES;

__global__ __launch_bounds__(256, 2)
void pass1_kernel(const float* __restrict__ q, const float* __restrict__ kmat,
                  const int* __restrict__ labels, float* __restrict__ ws)
{
    __shared__ float qs[C][LSTR];
    __shared__ float ks[C][LSTR];
    __shared__ float colred[4][CHUNK][4];
    __shared__ float nred[4][2];

    const int bidx = blockIdx.x;
    const int b    = bidx / TILES;
    const int tile = bidx % TILES;
    const int tid  = threadIdx.x;
    const int tx   = tid & 15;
    const int ty   = tid >> 4;
    const int lane = tid & 63;
    const int wave = tid >> 6;
    const int rowbase = tile * TILE_R;
    const int r0 = ty * 8;            // thread's first row within tile
    const int c0 = tx * 8;            // thread's first col within chunk

    float* colmax_p = ws + WS_COLMAX;
    float* colsum_p = ws + WS_COLSUM;
    float* colssq_p = ws + WS_COLSSQ;
    float* colp1_p  = ws + WS_COLP1;
    float* rowmax_p = ws + WS_ROWMAX;
    float* rowsum_p = ws + WS_ROWSUM;
    float* rowssq_p = ws + WS_ROWSSQ;
    float* rowp2_p  = ws + WS_ROWP2;
    float* negs_p   = ws + WS_NEGS;
    float* negc_p   = ws + WS_NEGC;

    // stage q tile, transposed: q[b][rowbase+r][c] -> qs[c][r]
    const float* qb = q + ((size_t)b * L + rowbase) * C;
    for (int it = tid; it < TILE_R * C; it += 256) {
        qs[it & 63][it >> 6] = qb[it];
    }

    float rmax[8], rsum[8], rssq[8], rp2[8];
#pragma unroll
    for (int i = 0; i < 8; ++i) { rmax[i] = -3.4e38f; rsum[i] = 0.f; rssq[i] = 0.f; rp2[i] = 0.f; }
    float negsum = 0.f, negcnt = 0.f;

    const float* kb = kmat + (size_t)b * S * C;
    const int*   lb = labels + ((size_t)b * L + rowbase) * S;

    for (int ch = 0; ch < NCHUNK; ++ch) {
        __syncthreads();   // protect ks + colred reuse
        const float* kc = kb + (size_t)ch * CHUNK * C;
        for (int it = tid; it < CHUNK * C; it += 256) {
            ks[it & 63][it >> 6] = kc[it];
        }
        __syncthreads();

        float acc[8][8];
#pragma unroll
        for (int i = 0; i < 8; ++i)
#pragma unroll
            for (int j = 0; j < 8; ++j) acc[i][j] = 0.f;

#pragma unroll 8
        for (int kk = 0; kk < C; ++kk) {
            float4 a0 = *(const float4*)&qs[kk][r0];
            float4 a1 = *(const float4*)&qs[kk][r0 + 4];
            float4 b0 = *(const float4*)&ks[kk][c0];
            float4 b1 = *(const float4*)&ks[kk][c0 + 4];
            float av[8] = {a0.x, a0.y, a0.z, a0.w, a1.x, a1.y, a1.z, a1.w};
            float bv[8] = {b0.x, b0.y, b0.z, b0.w, b1.x, b1.y, b1.z, b1.w};
#pragma unroll
            for (int i = 0; i < 8; ++i)
#pragma unroll
                for (int j = 0; j < 8; ++j)
                    acc[i][j] = fmaf(av[i], bv[j], acc[i][j]);
        }

        float cmax[8], csum[8], cssq[8], cp1[8];
#pragma unroll
        for (int j = 0; j < 8; ++j) { cmax[j] = -3.4e38f; csum[j] = 0.f; cssq[j] = 0.f; cp1[j] = 0.f; }

#pragma unroll
        for (int i = 0; i < 8; ++i) {
            const int* lrow = lb + (size_t)(r0 + i) * S + ch * CHUNK + c0;
            int4 l0 = *(const int4*)lrow;
            int4 l1 = *(const int4*)(lrow + 4);
            int labv[8] = {l0.x, l0.y, l0.z, l0.w, l1.x, l1.y, l1.z, l1.w};
#pragma unroll
            for (int j = 0; j < 8; ++j) {
                float sim = fmaf(0.5f, acc[i][j], 0.5f);
                rmax[i] = fmaxf(rmax[i], sim);
                rsum[i] += sim;
                rssq[i] = fmaf(sim, sim, rssq[i]);
                cmax[j] = fmaxf(cmax[j], sim);
                csum[j] += sim;
                cssq[j] = fmaf(sim, sim, cssq[j]);
                float sc  = fminf(fmaxf(sim, EPSF), 1.f - EPSF);
                bool  isp = (labv[j] == 1);
                float pos = isp ? 1.f : 0.f;
                float t   = isp ? sc : (1.f - sc);
                float nl  = -__logf(t);      // exactly one log per element
                float pn  = pos * nl;
                rp2[i] += pn;
                cp1[j] += pn;
                negsum += nl - pn;           // adds nl only when neg
                negcnt += 1.f - pos;
            }
        }

        // column reduce over ty: lanes differing in bits 4,5 within wave
#pragma unroll
        for (int j = 0; j < 8; ++j) {
#pragma unroll
            for (int m = 16; m <= 32; m <<= 1) {
                cmax[j] = fmaxf(cmax[j], __shfl_xor(cmax[j], m, 64));
                csum[j] += __shfl_xor(csum[j], m, 64);
                cssq[j] += __shfl_xor(cssq[j], m, 64);
                cp1[j]  += __shfl_xor(cp1[j],  m, 64);
            }
        }
        if (lane < 16) {   // tx == lane for these lanes
#pragma unroll
            for (int j = 0; j < 8; ++j) {
                colred[wave][lane * 8 + j][0] = cmax[j];
                colred[wave][lane * 8 + j][1] = csum[j];
                colred[wave][lane * 8 + j][2] = cssq[j];
                colred[wave][lane * 8 + j][3] = cp1[j];
            }
        }
        __syncthreads();
        if (tid < CHUNK) {
            float m0 = colred[0][tid][0], s1 = colred[0][tid][1];
            float s2 = colred[0][tid][2], pp = colred[0][tid][3];
#pragma unroll
            for (int w = 1; w < 4; ++w) {
                m0 = fmaxf(m0, colred[w][tid][0]);
                s1 += colred[w][tid][1];
                s2 += colred[w][tid][2];
                pp += colred[w][tid][3];
            }
            size_t idx = ((size_t)b * TILES + tile) * S + ch * CHUNK + tid;
            colmax_p[idx] = m0; colsum_p[idx] = s1; colssq_p[idx] = s2; colp1_p[idx] = pp;
        }
    }

    // row reduce over tx: 16-lane groups
#pragma unroll
    for (int i = 0; i < 8; ++i) {
#pragma unroll
        for (int m = 1; m <= 8; m <<= 1) {
            rmax[i] = fmaxf(rmax[i], __shfl_xor(rmax[i], m, 64));
            rsum[i] += __shfl_xor(rsum[i], m, 64);
            rssq[i] += __shfl_xor(rssq[i], m, 64);
            rp2[i]  += __shfl_xor(rp2[i],  m, 64);
        }
    }
    if (tx == 0) {
#pragma unroll
        for (int i = 0; i < 8; ++i) {
            size_t idx = (size_t)b * L + rowbase + r0 + i;
            rowmax_p[idx] = rmax[i]; rowsum_p[idx] = rsum[i];
            rowssq_p[idx] = rssq[i]; rowp2_p[idx]  = rp2[i];
        }
    }

    // negatives: full block reduce
#pragma unroll
    for (int m = 1; m <= 32; m <<= 1) {
        negsum += __shfl_xor(negsum, m, 64);
        negcnt += __shfl_xor(negcnt, m, 64);
    }
    if (lane == 0) { nred[wave][0] = negsum; nred[wave][1] = negcnt; }
    __syncthreads();
    if (tid == 0) {
        float ns = 0.f, nc = 0.f;
        for (int w = 0; w < 4; ++w) { ns += nred[w][0]; nc += nred[w][1]; }
        negs_p[bidx] = ns; negc_p[bidx] = nc;
    }
}

template <bool MAX>
__device__ inline float bred(float v, float* red)
{
#pragma unroll
    for (int m = 1; m <= 32; m <<= 1) {
        float o = __shfl_xor(v, m, 64);
        v = MAX ? fmaxf(v, o) : (v + o);
    }
    const int wave = threadIdx.x >> 6;
    const int lane = threadIdx.x & 63;
    if (lane == 0) red[wave] = v;
    __syncthreads();
    if (threadIdx.x == 0) {
        float r = red[0];
        for (int w = 1; w < 8; ++w) r = MAX ? fmaxf(r, red[w]) : (r + red[w]);
        red[8] = r;
    }
    __syncthreads();
    float out = red[8];
    __syncthreads();   // protect red[] before next reduction reuses it
    return out;
}

__global__ __launch_bounds__(512)
void pass2_kernel(const float* __restrict__ ws, float* __restrict__ out)
{
    __shared__ float red[9];
    const int b = blockIdx.x;
    const int s = threadIdx.x;

    const float* colmax_p = ws + WS_COLMAX;
    const float* colsum_p = ws + WS_COLSUM;
    const float* colssq_p = ws + WS_COLSSQ;
    const float* colp1_p  = ws + WS_COLP1;
    const float* rowmax_p = ws + WS_ROWMAX;
    const float* rowsum_p = ws + WS_ROWSUM;
    const float* rowssq_p = ws + WS_ROWSSQ;
    const float* rowp2_p  = ws + WS_ROWP2;
    const float* negs_p   = ws + WS_NEGS;
    const float* negc_p   = ws + WS_NEGC;

    // columns: combine 4 tile partials
    float m = -3.4e38f, sm = 0.f, sq = 0.f, p1 = 0.f;
#pragma unroll
    for (int t = 0; t < TILES; ++t) {
        size_t idx = ((size_t)b * TILES + t) * S + s;
        m = fmaxf(m, colmax_p[idx]);
        sm += colsum_p[idx];
        sq += colssq_p[idx];
        p1 += colp1_p[idx];
    }
    float mean  = sm * (1.f / L);
    float var   = (sq - sm * sm * (1.f / L)) * (1.f / (L - 1));
    float score = (m - mean) / sqrtf(var);

    float gmax = bred<true>(score, red);
    float e    = __expf(score - gmax);
    float esum = bred<false>(e, red);
    float sharp1 = e / esum;
    out[(size_t)b * S + s] = sharp1;
    float loss1 = bred<false>(sharp1 * p1, red);

    // rows
    size_t ridx = (size_t)b * L + s;
    float m2 = rowmax_p[ridx], sm2 = rowsum_p[ridx];
    float sq2 = rowssq_p[ridx], p2 = rowp2_p[ridx];
    float mean2  = sm2 * (1.f / S);
    float var2   = (sq2 - sm2 * sm2 * (1.f / S)) * (1.f / (S - 1));
    float score2 = (m2 - mean2) / sqrtf(var2);

    float gmax2 = bred<true>(score2, red);
    float e2    = __expf(score2 - gmax2);
    float esum2 = bred<false>(e2, red);
    float loss2 = bred<false>((e2 / esum2) * p2, red);

    if (s == 0) {
        float ns = 0.f, nc = 0.f;
        for (int t = 0; t < TILES; ++t) { ns += negs_p[b * TILES + t]; nc += negc_p[b * TILES + t]; }
        float lossb = 0.5f * (loss1 + loss2) + ns / nc;
        atomicAdd(out + (size_t)B * S, lossb * (1.f / B));
    }
}

extern "C" void kernel_launch(void* const* d_in, const int* in_sizes, int n_in,
                              void* d_out, int out_size, void* d_ws, size_t ws_size,
                              hipStream_t stream)
{
    const float* q      = (const float*)d_in[0];
    const float* k      = (const float*)d_in[1];
    const int*   labels = (const int*)d_in[2];
    float* out = (float*)d_out;
    float* ws  = (float*)d_ws;

    // zero the scalar-loss slot (harness poisons d_out before timed replays)
    hipMemsetAsync((char*)d_out + (size_t)B * S * sizeof(float), 0, sizeof(float), stream);

    pass1_kernel<<<dim3(B * TILES), dim3(256), 0, stream>>>(q, k, labels, ws);
    pass2_kernel<<<dim3(B), dim3(512), 0, stream>>>(ws, out);
}

// Round 2
// 285.991 us; speedup vs baseline: 1.2229x; 1.2229x over previous
//
#include <hip/hip_runtime.h>

#define EPSF 1e-6f

constexpr int B = 128, L = 512, S = 512, C = 64;
constexpr int TILE_R = 128;           // rows per pass-1 block
constexpr int TILES  = L / TILE_R;    // 4
constexpr int CHUNK  = 64;            // cols per k-chunk (8x4 per-thread tile -> no spills)
constexpr int NCHUNK = S / CHUNK;     // 8
constexpr int QSTR   = 132;           // padded LDS stride for q (16B-aligned float4 rows)
constexpr int KSTR   = 68;            // padded LDS stride for k

// workspace float offsets
constexpr size_t WS_COLMAX = 0;
constexpr size_t WS_COLSUM = WS_COLMAX + (size_t)B * TILES * S;
constexpr size_t WS_COLSSQ = WS_COLSUM + (size_t)B * TILES * S;
constexpr size_t WS_COLP1  = WS_COLSSQ + (size_t)B * TILES * S;
constexpr size_t WS_ROWMAX = WS_COLP1  + (size_t)B * TILES * S;
constexpr size_t WS_ROWSUM = WS_ROWMAX + (size_t)B * L;
constexpr size_t WS_ROWSSQ = WS_ROWSUM + (size_t)B * L;
constexpr size_t WS_ROWP2  = WS_ROWSSQ + (size_t)B * L;
constexpr size_t WS_NEGS   = WS_ROWP2  + (size_t)B * L;
constexpr size_t WS_NEGC   = WS_NEGS   + (size_t)B * TILES;

__global__ __launch_bounds__(256, 2)
void pass1_kernel(const float* __restrict__ q, const float* __restrict__ kmat,
                  const int* __restrict__ labels, float* __restrict__ ws)
{
    __shared__ float qs[C][QSTR];
    __shared__ float ks[C][KSTR];
    __shared__ float colred[4][CHUNK][4];
    __shared__ float nred[4][2];

    const int bidx = blockIdx.x;
    const int b    = bidx / TILES;
    const int tile = bidx % TILES;
    const int tid  = threadIdx.x;
    const int tx   = tid & 15;        // 16 threads across columns (4 cols each)
    const int ty   = tid >> 4;        // 16 threads across rows (8 rows each)
    const int lane = tid & 63;
    const int wave = tid >> 6;
    const int rowbase = tile * TILE_R;
    const int r0 = ty * 8;            // thread's first row within tile
    const int c0 = tx * 4;            // thread's first col within chunk

    float* colmax_p = ws + WS_COLMAX;
    float* colsum_p = ws + WS_COLSUM;
    float* colssq_p = ws + WS_COLSSQ;
    float* colp1_p  = ws + WS_COLP1;
    float* rowmax_p = ws + WS_ROWMAX;
    float* rowsum_p = ws + WS_ROWSUM;
    float* rowssq_p = ws + WS_ROWSSQ;
    float* rowp2_p  = ws + WS_ROWP2;
    float* negs_p   = ws + WS_NEGS;
    float* negc_p   = ws + WS_NEGC;

    // stage q tile, transposed: q[b][rowbase+r][c] -> qs[c][r]
    const float* qb = q + ((size_t)b * L + rowbase) * C;
    for (int it = tid; it < TILE_R * C; it += 256) {
        qs[it & 63][it >> 6] = qb[it];
    }

    float rmax[8], rsum[8], rssq[8], rp2[8];
#pragma unroll
    for (int i = 0; i < 8; ++i) { rmax[i] = -3.4e38f; rsum[i] = 0.f; rssq[i] = 0.f; rp2[i] = 0.f; }
    float negsum = 0.f, negcnt = 0.f;

    const float* kb = kmat + (size_t)b * S * C;
    const int*   lb = labels + ((size_t)b * L + rowbase) * S;

    for (int ch = 0; ch < NCHUNK; ++ch) {
        __syncthreads();   // protect ks + colred reuse
        const float* kc = kb + (size_t)ch * CHUNK * C;
        for (int it = tid; it < CHUNK * C; it += 256) {
            ks[it & 63][it >> 6] = kc[it];
        }
        __syncthreads();

        float acc[8][4];
#pragma unroll
        for (int i = 0; i < 8; ++i)
#pragma unroll
            for (int j = 0; j < 4; ++j) acc[i][j] = 0.f;

#pragma unroll 4
        for (int kk = 0; kk < C; ++kk) {
            float4 a0 = *(const float4*)&qs[kk][r0];
            float4 a1 = *(const float4*)&qs[kk][r0 + 4];
            float4 bb = *(const float4*)&ks[kk][c0];
#pragma unroll
            for (int j = 0; j < 4; ++j) {
                float bj = (j == 0) ? bb.x : (j == 1) ? bb.y : (j == 2) ? bb.z : bb.w;
                acc[0][j] = fmaf(a0.x, bj, acc[0][j]);
                acc[1][j] = fmaf(a0.y, bj, acc[1][j]);
                acc[2][j] = fmaf(a0.z, bj, acc[2][j]);
                acc[3][j] = fmaf(a0.w, bj, acc[3][j]);
                acc[4][j] = fmaf(a1.x, bj, acc[4][j]);
                acc[5][j] = fmaf(a1.y, bj, acc[5][j]);
                acc[6][j] = fmaf(a1.z, bj, acc[6][j]);
                acc[7][j] = fmaf(a1.w, bj, acc[7][j]);
            }
        }

        float cmax[4], csum[4], cssq[4], cp1[4];
#pragma unroll
        for (int j = 0; j < 4; ++j) { cmax[j] = -3.4e38f; csum[j] = 0.f; cssq[j] = 0.f; cp1[j] = 0.f; }

#pragma unroll
        for (int i = 0; i < 8; ++i) {
            const int* lrow = lb + (size_t)(r0 + i) * S + ch * CHUNK + c0;
            int4 lv = *(const int4*)lrow;
            int labv[4] = {lv.x, lv.y, lv.z, lv.w};
#pragma unroll
            for (int j = 0; j < 4; ++j) {
                float sim = fmaf(0.5f, acc[i][j], 0.5f);
                rmax[i] = fmaxf(rmax[i], sim);
                rsum[i] += sim;
                rssq[i] = fmaf(sim, sim, rssq[i]);
                cmax[j] = fmaxf(cmax[j], sim);
                csum[j] += sim;
                cssq[j] = fmaf(sim, sim, cssq[j]);
                float sc  = fminf(fmaxf(sim, EPSF), 1.f - EPSF);
                bool  isp = (labv[j] == 1);
                float pos = isp ? 1.f : 0.f;
                float t   = isp ? sc : (1.f - sc);
                float nl  = -__logf(t);      // exactly one log per element
                float pn  = pos * nl;
                rp2[i] += pn;
                cp1[j] += pn;
                negsum += nl - pn;           // adds nl only when neg
                negcnt += 1.f - pos;
            }
        }

        // column reduce across ty within wave: lanes differing in bits 4,5
#pragma unroll
        for (int j = 0; j < 4; ++j) {
#pragma unroll
            for (int m = 16; m <= 32; m <<= 1) {
                cmax[j] = fmaxf(cmax[j], __shfl_xor(cmax[j], m, 64));
                csum[j] += __shfl_xor(csum[j], m, 64);
                cssq[j] += __shfl_xor(cssq[j], m, 64);
                cp1[j]  += __shfl_xor(cp1[j],  m, 64);
            }
        }
        if (lane < 16) {   // tx == lane for these lanes
#pragma unroll
            for (int j = 0; j < 4; ++j) {
                colred[wave][lane * 4 + j][0] = cmax[j];
                colred[wave][lane * 4 + j][1] = csum[j];
                colred[wave][lane * 4 + j][2] = cssq[j];
                colred[wave][lane * 4 + j][3] = cp1[j];
            }
        }
        __syncthreads();
        if (tid < CHUNK) {
            float m0 = colred[0][tid][0], s1 = colred[0][tid][1];
            float s2 = colred[0][tid][2], pp = colred[0][tid][3];
#pragma unroll
            for (int w = 1; w < 4; ++w) {
                m0 = fmaxf(m0, colred[w][tid][0]);
                s1 += colred[w][tid][1];
                s2 += colred[w][tid][2];
                pp += colred[w][tid][3];
            }
            size_t idx = ((size_t)b * TILES + tile) * S + ch * CHUNK + tid;
            colmax_p[idx] = m0; colsum_p[idx] = s1; colssq_p[idx] = s2; colp1_p[idx] = pp;
        }
    }

    // row reduce across tx: 16-lane groups
#pragma unroll
    for (int i = 0; i < 8; ++i) {
#pragma unroll
        for (int m = 1; m <= 8; m <<= 1) {
            rmax[i] = fmaxf(rmax[i], __shfl_xor(rmax[i], m, 64));
            rsum[i] += __shfl_xor(rsum[i], m, 64);
            rssq[i] += __shfl_xor(rssq[i], m, 64);
            rp2[i]  += __shfl_xor(rp2[i],  m, 64);
        }
    }
    if (tx == 0) {
#pragma unroll
        for (int i = 0; i < 8; ++i) {
            size_t idx = (size_t)b * L + rowbase + r0 + i;
            rowmax_p[idx] = rmax[i]; rowsum_p[idx] = rsum[i];
            rowssq_p[idx] = rssq[i]; rowp2_p[idx]  = rp2[i];
        }
    }

    // negatives: full block reduce
#pragma unroll
    for (int m = 1; m <= 32; m <<= 1) {
        negsum += __shfl_xor(negsum, m, 64);
        negcnt += __shfl_xor(negcnt, m, 64);
    }
    if (lane == 0) { nred[wave][0] = negsum; nred[wave][1] = negcnt; }
    __syncthreads();
    if (tid == 0) {
        float ns = 0.f, nc = 0.f;
        for (int w = 0; w < 4; ++w) { ns += nred[w][0]; nc += nred[w][1]; }
        negs_p[bidx] = ns; negc_p[bidx] = nc;
    }
}

template <bool MAX>
__device__ inline float bred(float v, float* red)
{
#pragma unroll
    for (int m = 1; m <= 32; m <<= 1) {
        float o = __shfl_xor(v, m, 64);
        v = MAX ? fmaxf(v, o) : (v + o);
    }
    const int wave = threadIdx.x >> 6;
    const int lane = threadIdx.x & 63;
    if (lane == 0) red[wave] = v;
    __syncthreads();
    if (threadIdx.x == 0) {
        float r = red[0];
        for (int w = 1; w < 8; ++w) r = MAX ? fmaxf(r, red[w]) : (r + red[w]);
        red[8] = r;
    }
    __syncthreads();
    float out = red[8];
    __syncthreads();   // protect red[] before next reduction reuses it
    return out;
}

// grid (B, 2): y==0 -> column path (sharp1 + loss1), y==1 -> row path (loss2 + loss3)
__global__ __launch_bounds__(512)
void pass2_kernel(const float* __restrict__ ws, float* __restrict__ out)
{
    __shared__ float red[9];
    const int b = blockIdx.x;
    const int s = threadIdx.x;

    if (blockIdx.y == 0) {
        const float* colmax_p = ws + WS_COLMAX;
        const float* colsum_p = ws + WS_COLSUM;
        const float* colssq_p = ws + WS_COLSSQ;
        const float* colp1_p  = ws + WS_COLP1;

        float m = -3.4e38f, sm = 0.f, sq = 0.f, p1 = 0.f;
#pragma unroll
        for (int t = 0; t < TILES; ++t) {
            size_t idx = ((size_t)b * TILES + t) * S + s;
            m = fmaxf(m, colmax_p[idx]);
            sm += colsum_p[idx];
            sq += colssq_p[idx];
            p1 += colp1_p[idx];
        }
        float mean  = sm * (1.f / L);
        float var   = (sq - sm * sm * (1.f / L)) * (1.f / (L - 1));
        float score = (m - mean) / sqrtf(var);

        float gmax = bred<true>(score, red);
        float e    = __expf(score - gmax);
        float esum = bred<false>(e, red);
        float sharp1 = e / esum;
        out[(size_t)b * S + s] = sharp1;
        float loss1 = bred<false>(sharp1 * p1, red);
        if (s == 0) atomicAdd(out + (size_t)B * S, loss1 * (0.5f / B));
    } else {
        const float* rowmax_p = ws + WS_ROWMAX;
        const float* rowsum_p = ws + WS_ROWSUM;
        const float* rowssq_p = ws + WS_ROWSSQ;
        const float* rowp2_p  = ws + WS_ROWP2;
        const float* negs_p   = ws + WS_NEGS;
        const float* negc_p   = ws + WS_NEGC;

        size_t ridx = (size_t)b * L + s;
        float m2 = rowmax_p[ridx], sm2 = rowsum_p[ridx];
        float sq2 = rowssq_p[ridx], p2 = rowp2_p[ridx];
        float mean2  = sm2 * (1.f / S);
        float var2   = (sq2 - sm2 * sm2 * (1.f / S)) * (1.f / (S - 1));
        float score2 = (m2 - mean2) / sqrtf(var2);

        float gmax2 = bred<true>(score2, red);
        float e2    = __expf(score2 - gmax2);
        float esum2 = bred<false>(e2, red);
        float loss2 = bred<false>((e2 / esum2) * p2, red);

        if (s == 0) {
            float ns = 0.f, nc = 0.f;
            for (int t = 0; t < TILES; ++t) { ns += negs_p[b * TILES + t]; nc += negc_p[b * TILES + t]; }
            atomicAdd(out + (size_t)B * S, (0.5f * loss2 + ns / nc) * (1.f / B));
        }
    }
}

extern "C" void kernel_launch(void* const* d_in, const int* in_sizes, int n_in,
                              void* d_out, int out_size, void* d_ws, size_t ws_size,
                              hipStream_t stream)
{
    const float* q      = (const float*)d_in[0];
    const float* k      = (const float*)d_in[1];
    const int*   labels = (const int*)d_in[2];
    float* out = (float*)d_out;
    float* ws  = (float*)d_ws;

    // zero the scalar-loss slot (harness poisons d_out before timed replays)
    hipMemsetAsync((char*)d_out + (size_t)B * S * sizeof(float), 0, sizeof(float), stream);

    pass1_kernel<<<dim3(B * TILES), dim3(256), 0, stream>>>(q, k, labels, ws);
    pass2_kernel<<<dim3(B, 2), dim3(512), 0, stream>>>(ws, out);
}

// Round 3
// 282.100 us; speedup vs baseline: 1.2397x; 1.0138x over previous
//
#include <hip/hip_runtime.h>

#define EPSF 1e-6f

constexpr int B = 128, L = 512, S = 512, C = 64;
constexpr int TILE_R = 64;            // rows per pass-1 block
constexpr int TILES  = L / TILE_R;    // 8
constexpr int CHUNK  = 64;            // cols per k-chunk
constexpr int NCHUNK = S / CHUNK;     // 8
constexpr int STR    = 68;            // padded LDS stride (16B-aligned b128, conflict-free reads)

// workspace float offsets
constexpr size_t WS_COLMAX = 0;
constexpr size_t WS_COLSUM = WS_COLMAX + (size_t)B * TILES * S;
constexpr size_t WS_COLSSQ = WS_COLSUM + (size_t)B * TILES * S;
constexpr size_t WS_COLP1  = WS_COLSSQ + (size_t)B * TILES * S;
constexpr size_t WS_ROWMAX = WS_COLP1  + (size_t)B * TILES * S;
constexpr size_t WS_ROWSUM = WS_ROWMAX + (size_t)B * L;
constexpr size_t WS_ROWSSQ = WS_ROWSUM + (size_t)B * L;
constexpr size_t WS_ROWP2  = WS_ROWSSQ + (size_t)B * L;
constexpr size_t WS_NEGS   = WS_ROWP2  + (size_t)B * L;
constexpr size_t WS_NEGC   = WS_NEGS   + (size_t)B * TILES;

// Stage a 64x64 fp32 tile from global (row-major [r][c]) into LDS transposed
// ([c][r], stride STR). Each thread: 4x4 block -> 4 dwordx4 loads, register
// transpose, 4 ds_write_b128 (conflict-free: lanes 0-15 cover 64 consecutive
// dwords per instruction).
__device__ inline void stage_T(const float* __restrict__ g, float (*lds)[STR], int tid)
{
    const int r0 = (tid & 15) * 4;
    const int c0 = (tid >> 4) * 4;
    float4 r0v = *(const float4*)&g[(r0 + 0) * 64 + c0];
    float4 r1v = *(const float4*)&g[(r0 + 1) * 64 + c0];
    float4 r2v = *(const float4*)&g[(r0 + 2) * 64 + c0];
    float4 r3v = *(const float4*)&g[(r0 + 3) * 64 + c0];
    *(float4*)&lds[c0 + 0][r0] = make_float4(r0v.x, r1v.x, r2v.x, r3v.x);
    *(float4*)&lds[c0 + 1][r0] = make_float4(r0v.y, r1v.y, r2v.y, r3v.y);
    *(float4*)&lds[c0 + 2][r0] = make_float4(r0v.z, r1v.z, r2v.z, r3v.z);
    *(float4*)&lds[c0 + 3][r0] = make_float4(r0v.w, r1v.w, r2v.w, r3v.w);
}

__global__ __launch_bounds__(256, 4)
void pass1_kernel(const float* __restrict__ q, const float* __restrict__ kmat,
                  const int* __restrict__ labels, float* __restrict__ ws)
{
    __shared__ float qs[C][STR];
    __shared__ float ks[C][STR];
    __shared__ float colred[4][CHUNK][4];
    __shared__ float nred[4][2];

    const int bidx = blockIdx.x;
    const int b    = bidx / TILES;
    const int tile = bidx % TILES;
    const int tid  = threadIdx.x;
    const int tx   = tid & 15;        // 16 threads across columns (4 cols each)
    const int ty   = tid >> 4;        // 16 threads across rows (4 rows each)
    const int lane = tid & 63;
    const int wave = tid >> 6;
    const int rowbase = tile * TILE_R;
    const int r0 = ty * 4;            // thread's first row within tile
    const int c0 = tx * 4;            // thread's first col within chunk

    float* colmax_p = ws + WS_COLMAX;
    float* colsum_p = ws + WS_COLSUM;
    float* colssq_p = ws + WS_COLSSQ;
    float* colp1_p  = ws + WS_COLP1;
    float* rowmax_p = ws + WS_ROWMAX;
    float* rowsum_p = ws + WS_ROWSUM;
    float* rowssq_p = ws + WS_ROWSSQ;
    float* rowp2_p  = ws + WS_ROWP2;
    float* negs_p   = ws + WS_NEGS;
    float* negc_p   = ws + WS_NEGC;

    // stage q tile transposed: q[b][rowbase+r][c] -> qs[c][r]
    stage_T(q + ((size_t)b * L + rowbase) * C, qs, tid);

    float rmax[4], rsum[4], rssq[4], rp2[4];
#pragma unroll
    for (int i = 0; i < 4; ++i) { rmax[i] = -3.4e38f; rsum[i] = 0.f; rssq[i] = 0.f; rp2[i] = 0.f; }
    float negsum = 0.f, negcnt = 0.f;

    const float* kb = kmat + (size_t)b * S * C;
    const int*   lb = labels + ((size_t)b * L + rowbase) * S;

    for (int ch = 0; ch < NCHUNK; ++ch) {
        __syncthreads();   // protect ks + colred reuse
        stage_T(kb + (size_t)ch * CHUNK * C, ks, tid);
        __syncthreads();

        float acc[4][4];
#pragma unroll
        for (int i = 0; i < 4; ++i)
#pragma unroll
            for (int j = 0; j < 4; ++j) acc[i][j] = 0.f;

#pragma unroll 4
        for (int kk = 0; kk < C; ++kk) {
            float4 av = *(const float4*)&qs[kk][r0];   // broadcast within 16-lane group
            float4 bv = *(const float4*)&ks[kk][c0];   // 64 consecutive dwords per group
            float a[4] = {av.x, av.y, av.z, av.w};
            float bb[4] = {bv.x, bv.y, bv.z, bv.w};
#pragma unroll
            for (int i = 0; i < 4; ++i)
#pragma unroll
                for (int j = 0; j < 4; ++j)
                    acc[i][j] = fmaf(a[i], bb[j], acc[i][j]);
        }

        float cmax[4], csum[4], cssq[4], cp1[4];
#pragma unroll
        for (int j = 0; j < 4; ++j) { cmax[j] = -3.4e38f; csum[j] = 0.f; cssq[j] = 0.f; cp1[j] = 0.f; }

#pragma unroll
        for (int i = 0; i < 4; ++i) {
            const int* lrow = lb + (size_t)(r0 + i) * S + ch * CHUNK + c0;
            int4 lv = *(const int4*)lrow;
            int labv[4] = {lv.x, lv.y, lv.z, lv.w};
#pragma unroll
            for (int j = 0; j < 4; ++j) {
                float sim = fmaf(0.5f, acc[i][j], 0.5f);
                rmax[i] = fmaxf(rmax[i], sim);
                rsum[i] += sim;
                rssq[i] = fmaf(sim, sim, rssq[i]);
                cmax[j] = fmaxf(cmax[j], sim);
                csum[j] += sim;
                cssq[j] = fmaf(sim, sim, cssq[j]);
                float sc  = fminf(fmaxf(sim, EPSF), 1.f - EPSF);
                bool  isp = (labv[j] == 1);
                float pos = isp ? 1.f : 0.f;
                float t   = isp ? sc : (1.f - sc);
                float nl  = -__logf(t);      // one log per element
                float pn  = pos * nl;
                rp2[i] += pn;
                cp1[j] += pn;
                negsum += nl - pn;           // adds nl only when neg
                negcnt += 1.f - pos;
            }
        }

        // column reduce across ty-within-wave (lane bits 4,5), then LDS across waves
#pragma unroll
        for (int j = 0; j < 4; ++j) {
#pragma unroll
            for (int m = 16; m <= 32; m <<= 1) {
                cmax[j] = fmaxf(cmax[j], __shfl_xor(cmax[j], m, 64));
                csum[j] += __shfl_xor(csum[j], m, 64);
                cssq[j] += __shfl_xor(cssq[j], m, 64);
                cp1[j]  += __shfl_xor(cp1[j],  m, 64);
            }
        }
        if (lane < 16) {   // tx == lane for these lanes
#pragma unroll
            for (int j = 0; j < 4; ++j) {
                colred[wave][lane * 4 + j][0] = cmax[j];
                colred[wave][lane * 4 + j][1] = csum[j];
                colred[wave][lane * 4 + j][2] = cssq[j];
                colred[wave][lane * 4 + j][3] = cp1[j];
            }
        }
        __syncthreads();
        if (tid < CHUNK) {
            float m0 = colred[0][tid][0], s1 = colred[0][tid][1];
            float s2 = colred[0][tid][2], pp = colred[0][tid][3];
#pragma unroll
            for (int w = 1; w < 4; ++w) {
                m0 = fmaxf(m0, colred[w][tid][0]);
                s1 += colred[w][tid][1];
                s2 += colred[w][tid][2];
                pp += colred[w][tid][3];
            }
            size_t idx = ((size_t)b * TILES + tile) * S + ch * CHUNK + tid;
            colmax_p[idx] = m0; colsum_p[idx] = s1; colssq_p[idx] = s2; colp1_p[idx] = pp;
        }
    }

    // row reduce across tx: 16-lane groups
#pragma unroll
    for (int i = 0; i < 4; ++i) {
#pragma unroll
        for (int m = 1; m <= 8; m <<= 1) {
            rmax[i] = fmaxf(rmax[i], __shfl_xor(rmax[i], m, 64));
            rsum[i] += __shfl_xor(rsum[i], m, 64);
            rssq[i] += __shfl_xor(rssq[i], m, 64);
            rp2[i]  += __shfl_xor(rp2[i],  m, 64);
        }
    }
    if (tx == 0) {
#pragma unroll
        for (int i = 0; i < 4; ++i) {
            size_t idx = (size_t)b * L + rowbase + r0 + i;
            rowmax_p[idx] = rmax[i]; rowsum_p[idx] = rsum[i];
            rowssq_p[idx] = rssq[i]; rowp2_p[idx]  = rp2[i];
        }
    }

    // negatives: full block reduce
#pragma unroll
    for (int m = 1; m <= 32; m <<= 1) {
        negsum += __shfl_xor(negsum, m, 64);
        negcnt += __shfl_xor(negcnt, m, 64);
    }
    if (lane == 0) { nred[wave][0] = negsum; nred[wave][1] = negcnt; }
    __syncthreads();
    if (tid == 0) {
        float ns = 0.f, nc = 0.f;
        for (int w = 0; w < 4; ++w) { ns += nred[w][0]; nc += nred[w][1]; }
        negs_p[bidx] = ns; negc_p[bidx] = nc;
    }
}

template <bool MAX>
__device__ inline float bred(float v, float* red)
{
#pragma unroll
    for (int m = 1; m <= 32; m <<= 1) {
        float o = __shfl_xor(v, m, 64);
        v = MAX ? fmaxf(v, o) : (v + o);
    }
    const int wave = threadIdx.x >> 6;
    const int lane = threadIdx.x & 63;
    if (lane == 0) red[wave] = v;
    __syncthreads();
    if (threadIdx.x == 0) {
        float r = red[0];
        for (int w = 1; w < 8; ++w) r = MAX ? fmaxf(r, red[w]) : (r + red[w]);
        red[8] = r;
    }
    __syncthreads();
    float out = red[8];
    __syncthreads();   // protect red[] before next reduction reuses it
    return out;
}

// grid (B, 2): y==0 -> column path (sharp1 + loss1), y==1 -> row path (loss2 + loss3)
__global__ __launch_bounds__(512)
void pass2_kernel(const float* __restrict__ ws, float* __restrict__ out)
{
    __shared__ float red[9];
    const int b = blockIdx.x;
    const int s = threadIdx.x;

    if (blockIdx.y == 0) {
        const float* colmax_p = ws + WS_COLMAX;
        const float* colsum_p = ws + WS_COLSUM;
        const float* colssq_p = ws + WS_COLSSQ;
        const float* colp1_p  = ws + WS_COLP1;

        float m = -3.4e38f, sm = 0.f, sq = 0.f, p1 = 0.f;
#pragma unroll
        for (int t = 0; t < TILES; ++t) {
            size_t idx = ((size_t)b * TILES + t) * S + s;
            m = fmaxf(m, colmax_p[idx]);
            sm += colsum_p[idx];
            sq += colssq_p[idx];
            p1 += colp1_p[idx];
        }
        float mean  = sm * (1.f / L);
        float var   = (sq - sm * sm * (1.f / L)) * (1.f / (L - 1));
        float score = (m - mean) / sqrtf(var);

        float gmax = bred<true>(score, red);
        float e    = __expf(score - gmax);
        float esum = bred<false>(e, red);
        float sharp1 = e / esum;
        out[(size_t)b * S + s] = sharp1;
        float loss1 = bred<false>(sharp1 * p1, red);
        if (s == 0) atomicAdd(out + (size_t)B * S, loss1 * (0.5f / B));
    } else {
        const float* rowmax_p = ws + WS_ROWMAX;
        const float* rowsum_p = ws + WS_ROWSUM;
        const float* rowssq_p = ws + WS_ROWSSQ;
        const float* rowp2_p  = ws + WS_ROWP2;
        const float* negs_p   = ws + WS_NEGS;
        const float* negc_p   = ws + WS_NEGC;

        size_t ridx = (size_t)b * L + s;
        float m2 = rowmax_p[ridx], sm2 = rowsum_p[ridx];
        float sq2 = rowssq_p[ridx], p2 = rowp2_p[ridx];
        float mean2  = sm2 * (1.f / S);
        float var2   = (sq2 - sm2 * sm2 * (1.f / S)) * (1.f / (S - 1));
        float score2 = (m2 - mean2) / sqrtf(var2);

        float gmax2 = bred<true>(score2, red);
        float e2    = __expf(score2 - gmax2);
        float esum2 = bred<false>(e2, red);
        float loss2 = bred<false>((e2 / esum2) * p2, red);

        if (s == 0) {
            float ns = 0.f, nc = 0.f;
            for (int t = 0; t < TILES; ++t) { ns += negs_p[b * TILES + t]; nc += negc_p[b * TILES + t]; }
            atomicAdd(out + (size_t)B * S, (0.5f * loss2 + ns / nc) * (1.f / B));
        }
    }
}

extern "C" void kernel_launch(void* const* d_in, const int* in_sizes, int n_in,
                              void* d_out, int out_size, void* d_ws, size_t ws_size,
                              hipStream_t stream)
{
    const float* q      = (const float*)d_in[0];
    const float* k      = (const float*)d_in[1];
    const int*   labels = (const int*)d_in[2];
    float* out = (float*)d_out;
    float* ws  = (float*)d_ws;

    // zero the scalar-loss slot (harness poisons d_out before timed replays)
    hipMemsetAsync((char*)d_out + (size_t)B * S * sizeof(float), 0, sizeof(float), stream);

    pass1_kernel<<<dim3(B * TILES), dim3(256), 0, stream>>>(q, k, labels, ws);
    pass2_kernel<<<dim3(B, 2), dim3(512), 0, stream>>>(ws, out);
}

// Round 4
// 274.503 us; speedup vs baseline: 1.2740x; 1.0277x over previous
//
#include <hip/hip_runtime.h>

#define EPSF 1e-6f

typedef _Float16 half8 __attribute__((ext_vector_type(8)));
typedef float f32x4 __attribute__((ext_vector_type(4)));

constexpr int B = 128, L = 512, S = 512, C = 64;
constexpr int TILE_R = 64;            // rows per pass-1 block
constexpr int TILES  = L / TILE_R;    // 8
constexpr int CHUNK  = 64;            // cols per k-chunk
constexpr int NCHUNK = S / CHUNK;     // 8

// workspace float offsets
constexpr size_t WS_COLMAX = 0;
constexpr size_t WS_COLSUM = WS_COLMAX + (size_t)B * TILES * S;
constexpr size_t WS_COLSSQ = WS_COLSUM + (size_t)B * TILES * S;
constexpr size_t WS_COLP1  = WS_COLSSQ + (size_t)B * TILES * S;
constexpr size_t WS_ROWMAX = WS_COLP1  + (size_t)B * TILES * S;
constexpr size_t WS_ROWSUM = WS_ROWMAX + (size_t)B * L;
constexpr size_t WS_ROWSSQ = WS_ROWSUM + (size_t)B * L;
constexpr size_t WS_ROWP2  = WS_ROWSSQ + (size_t)B * L;
constexpr size_t WS_NEGS   = WS_ROWP2  + (size_t)B * L;
constexpr size_t WS_NEGC   = WS_NEGS   + (size_t)B * TILES;

// Stage a 64x64 fp32 tile (row-major [row][c]) into frag-swizzled fp16 hi/lo LDS.
// Layout: arr[(row>>4)*2 + (c>>5)][ (( (c>>3)&3 )<<4) + (row&15) ][c&7]
// so an MFMA A/B fragment read is one lane-linear ds_read_b128 (conflict-free).
// Split: v = hi + lo with hi = fp16(v), lo = fp16(v - hi)  (~2^-22 rel err).
__device__ inline void stageF(const float* __restrict__ g,
                              half8 (*__restrict__ hiA)[64],
                              half8 (*__restrict__ loA)[64], int t)
{
    const int row = t >> 2, c0 = (t & 3) * 16;
    const float* src = g + row * 64 + c0;
    float4 v0 = *(const float4*)(src);
    float4 v1 = *(const float4*)(src + 4);
    float4 v2 = *(const float4*)(src + 8);
    float4 v3 = *(const float4*)(src + 12);
    float v[16] = {v0.x, v0.y, v0.z, v0.w, v1.x, v1.y, v1.z, v1.w,
                   v2.x, v2.y, v2.z, v2.w, v3.x, v3.y, v3.z, v3.w};
#pragma unroll
    for (int o = 0; o < 2; ++o) {
        const int cb   = c0 + o * 8;
        const int idx  = (row >> 4) * 2 + (cb >> 5);
        const int lane_s = (((cb >> 3) & 3) << 4) + (row & 15);
        half8 h, l;
#pragma unroll
        for (int j = 0; j < 8; ++j) {
            float f = v[o * 8 + j];
            _Float16 hi = (_Float16)f;
            h[j] = hi;
            l[j] = (_Float16)(f - (float)hi);
        }
        hiA[idx][lane_s] = h;
        loA[idx][lane_s] = l;
    }
}

__global__ __launch_bounds__(256, 4)
void pass1_kernel(const float* __restrict__ q, const float* __restrict__ kmat,
                  const int* __restrict__ labels, float* __restrict__ ws)
{
    __shared__ half8 qhiF[8][64], qloF[8][64];   // [wave*2+kstep][lane]
    __shared__ half8 khiF[8][64], kloF[8][64];   // [ct*2+kstep][lane]
    __shared__ float4 colred4[4][CHUNK];
    __shared__ float nred[4][2];

    const int bidx = blockIdx.x;
    const int b    = bidx / TILES;
    const int tile = bidx % TILES;
    const int tid  = threadIdx.x;
    const int lane = tid & 63;
    const int wave = tid >> 6;
    const int l15  = lane & 15;
    const int quad = lane >> 4;
    const int rowbase = tile * TILE_R;

    float* colmax_p = ws + WS_COLMAX;
    float* colsum_p = ws + WS_COLSUM;
    float* colssq_p = ws + WS_COLSSQ;
    float* colp1_p  = ws + WS_COLP1;
    float* rowmax_p = ws + WS_ROWMAX;
    float* rowsum_p = ws + WS_ROWSUM;
    float* rowssq_p = ws + WS_ROWSSQ;
    float* rowp2_p  = ws + WS_ROWP2;
    float* negs_p   = ws + WS_NEGS;
    float* negc_p   = ws + WS_NEGC;

    // stage q tile (constant across chunks)
    stageF(q + ((size_t)b * L + rowbase) * C, qhiF, qloF, tid);

    float rmax[4], rsum[4], rssq[4], rp2[4];
#pragma unroll
    for (int i = 0; i < 4; ++i) { rmax[i] = -3.4e38f; rsum[i] = 0.f; rssq[i] = 0.f; rp2[i] = 0.f; }
    float negsum = 0.f, negcnt = 0.f;

    const float* kb = kmat + (size_t)b * S * C;
    const int*   lb = labels + ((size_t)b * L + rowbase) * S;

    for (int ch = 0; ch < NCHUNK; ++ch) {
        __syncthreads();   // protect k re-stage + colred reuse (+ q writes on iter 0)
        stageF(kb + (size_t)ch * CHUNK * C, khiF, kloF, tid);
        __syncthreads();

        // A fragments: this wave's 16 rows, 2 K-steps, hi+lo
        half8 ah0 = qhiF[wave * 2 + 0][lane], ah1 = qhiF[wave * 2 + 1][lane];
        half8 al0 = qloF[wave * 2 + 0][lane], al1 = qloF[wave * 2 + 1][lane];

        f32x4 acc[4];
#pragma unroll
        for (int ct = 0; ct < 4; ++ct) {
            half8 bh0 = khiF[ct * 2 + 0][lane], bh1 = khiF[ct * 2 + 1][lane];
            half8 bl0 = kloF[ct * 2 + 0][lane], bl1 = kloF[ct * 2 + 1][lane];
            f32x4 a = {0.f, 0.f, 0.f, 0.f};
            a = __builtin_amdgcn_mfma_f32_16x16x32_f16(ah0, bh0, a, 0, 0, 0);
            a = __builtin_amdgcn_mfma_f32_16x16x32_f16(ah0, bl0, a, 0, 0, 0);
            a = __builtin_amdgcn_mfma_f32_16x16x32_f16(al0, bh0, a, 0, 0, 0);
            a = __builtin_amdgcn_mfma_f32_16x16x32_f16(ah1, bh1, a, 0, 0, 0);
            a = __builtin_amdgcn_mfma_f32_16x16x32_f16(ah1, bl1, a, 0, 0, 0);
            a = __builtin_amdgcn_mfma_f32_16x16x32_f16(al1, bh1, a, 0, 0, 0);
            acc[ct] = a;
        }

        // epilogue: C/D layout col = l15, row = quad*4 + r  [m89-verified]
        float cmax[4], csum[4], cssq[4], cp1[4];
#pragma unroll
        for (int ct = 0; ct < 4; ++ct) { cmax[ct] = -3.4e38f; csum[ct] = 0.f; cssq[ct] = 0.f; cp1[ct] = 0.f; }

#pragma unroll
        for (int ct = 0; ct < 4; ++ct) {
            const int colg = ch * CHUNK + ct * 16 + l15;
#pragma unroll
            for (int r = 0; r < 4; ++r) {
                const int rowl = wave * 16 + quad * 4 + r;
                int lab = lb[(size_t)rowl * S + colg];
                float sim = fmaf(0.5f, acc[ct][r], 0.5f);
                rmax[r] = fmaxf(rmax[r], sim);
                rsum[r] += sim;
                rssq[r] = fmaf(sim, sim, rssq[r]);
                cmax[ct] = fmaxf(cmax[ct], sim);
                csum[ct] += sim;
                cssq[ct] = fmaf(sim, sim, cssq[ct]);
                float sc  = fminf(fmaxf(sim, EPSF), 1.f - EPSF);
                bool  isp = (lab == 1);
                float pos = isp ? 1.f : 0.f;
                float t   = isp ? sc : (1.f - sc);
                float nl  = -__logf(t);      // one log per element
                float pn  = pos * nl;
                rp2[r] += pn;
                cp1[ct] += pn;
                negsum += nl - pn;           // adds nl only when neg
                negcnt += 1.f - pos;
            }
        }

        // column reduce across quads (lanes sharing l15): xor 16, 32
#pragma unroll
        for (int ct = 0; ct < 4; ++ct) {
#pragma unroll
            for (int m = 16; m <= 32; m <<= 1) {
                cmax[ct] = fmaxf(cmax[ct], __shfl_xor(cmax[ct], m, 64));
                csum[ct] += __shfl_xor(csum[ct], m, 64);
                cssq[ct] += __shfl_xor(cssq[ct], m, 64);
                cp1[ct]  += __shfl_xor(cp1[ct],  m, 64);
            }
        }
        if (lane < 16) {
#pragma unroll
            for (int ct = 0; ct < 4; ++ct)
                colred4[wave][ct * 16 + l15] = make_float4(cmax[ct], csum[ct], cssq[ct], cp1[ct]);
        }
        __syncthreads();
        if (tid < CHUNK) {
            float4 v = colred4[0][tid];
            float m0 = v.x, s1 = v.y, s2 = v.z, pp = v.w;
#pragma unroll
            for (int w = 1; w < 4; ++w) {
                float4 u = colred4[w][tid];
                m0 = fmaxf(m0, u.x); s1 += u.y; s2 += u.z; pp += u.w;
            }
            size_t idx = ((size_t)b * TILES + tile) * S + ch * CHUNK + tid;
            colmax_p[idx] = m0; colsum_p[idx] = s1; colssq_p[idx] = s2; colp1_p[idx] = pp;
        }
    }

    // row reduce across l15 (lanes sharing quad): xor 1,2,4,8
#pragma unroll
    for (int r = 0; r < 4; ++r) {
#pragma unroll
        for (int m = 1; m <= 8; m <<= 1) {
            rmax[r] = fmaxf(rmax[r], __shfl_xor(rmax[r], m, 64));
            rsum[r] += __shfl_xor(rsum[r], m, 64);
            rssq[r] += __shfl_xor(rssq[r], m, 64);
            rp2[r]  += __shfl_xor(rp2[r],  m, 64);
        }
    }
    if (l15 == 0) {
#pragma unroll
        for (int r = 0; r < 4; ++r) {
            size_t idx = (size_t)b * L + rowbase + wave * 16 + quad * 4 + r;
            rowmax_p[idx] = rmax[r]; rowsum_p[idx] = rsum[r];
            rowssq_p[idx] = rssq[r]; rowp2_p[idx]  = rp2[r];
        }
    }

    // negatives: full block reduce
#pragma unroll
    for (int m = 1; m <= 32; m <<= 1) {
        negsum += __shfl_xor(negsum, m, 64);
        negcnt += __shfl_xor(negcnt, m, 64);
    }
    if (lane == 0) { nred[wave][0] = negsum; nred[wave][1] = negcnt; }
    __syncthreads();
    if (tid == 0) {
        float ns = 0.f, nc = 0.f;
        for (int w = 0; w < 4; ++w) { ns += nred[w][0]; nc += nred[w][1]; }
        negs_p[bidx] = ns; negc_p[bidx] = nc;
    }
}

template <bool MAX>
__device__ inline float bred(float v, float* red)
{
#pragma unroll
    for (int m = 1; m <= 32; m <<= 1) {
        float o = __shfl_xor(v, m, 64);
        v = MAX ? fmaxf(v, o) : (v + o);
    }
    const int wave = threadIdx.x >> 6;
    const int lane = threadIdx.x & 63;
    if (lane == 0) red[wave] = v;
    __syncthreads();
    if (threadIdx.x == 0) {
        float r = red[0];
        for (int w = 1; w < 8; ++w) r = MAX ? fmaxf(r, red[w]) : (r + red[w]);
        red[8] = r;
    }
    __syncthreads();
    float out = red[8];
    __syncthreads();   // protect red[] before next reduction reuses it
    return out;
}

// grid (B, 2): y==0 -> column path (sharp1 + loss1), y==1 -> row path (loss2 + loss3)
__global__ __launch_bounds__(512)
void pass2_kernel(const float* __restrict__ ws, float* __restrict__ out)
{
    __shared__ float red[9];
    const int b = blockIdx.x;
    const int s = threadIdx.x;

    if (blockIdx.y == 0) {
        const float* colmax_p = ws + WS_COLMAX;
        const float* colsum_p = ws + WS_COLSUM;
        const float* colssq_p = ws + WS_COLSSQ;
        const float* colp1_p  = ws + WS_COLP1;

        float m = -3.4e38f, sm = 0.f, sq = 0.f, p1 = 0.f;
#pragma unroll
        for (int t = 0; t < TILES; ++t) {
            size_t idx = ((size_t)b * TILES + t) * S + s;
            m = fmaxf(m, colmax_p[idx]);
            sm += colsum_p[idx];
            sq += colssq_p[idx];
            p1 += colp1_p[idx];
        }
        float mean  = sm * (1.f / L);
        float var   = (sq - sm * sm * (1.f / L)) * (1.f / (L - 1));
        float score = (m - mean) / sqrtf(var);

        float gmax = bred<true>(score, red);
        float e    = __expf(score - gmax);
        float esum = bred<false>(e, red);
        float sharp1 = e / esum;
        out[(size_t)b * S + s] = sharp1;
        float loss1 = bred<false>(sharp1 * p1, red);
        if (s == 0) atomicAdd(out + (size_t)B * S, loss1 * (0.5f / B));
    } else {
        const float* rowmax_p = ws + WS_ROWMAX;
        const float* rowsum_p = ws + WS_ROWSUM;
        const float* rowssq_p = ws + WS_ROWSSQ;
        const float* rowp2_p  = ws + WS_ROWP2;
        const float* negs_p   = ws + WS_NEGS;
        const float* negc_p   = ws + WS_NEGC;

        size_t ridx = (size_t)b * L + s;
        float m2 = rowmax_p[ridx], sm2 = rowsum_p[ridx];
        float sq2 = rowssq_p[ridx], p2 = rowp2_p[ridx];
        float mean2  = sm2 * (1.f / S);
        float var2   = (sq2 - sm2 * sm2 * (1.f / S)) * (1.f / (S - 1));
        float score2 = (m2 - mean2) / sqrtf(var2);

        float gmax2 = bred<true>(score2, red);
        float e2    = __expf(score2 - gmax2);
        float esum2 = bred<false>(e2, red);
        float loss2 = bred<false>((e2 / esum2) * p2, red);

        if (s == 0) {
            float ns = 0.f, nc = 0.f;
            for (int t = 0; t < TILES; ++t) { ns += negs_p[b * TILES + t]; nc += negc_p[b * TILES + t]; }
            atomicAdd(out + (size_t)B * S, (0.5f * loss2 + ns / nc) * (1.f / B));
        }
    }
}

extern "C" void kernel_launch(void* const* d_in, const int* in_sizes, int n_in,
                              void* d_out, int out_size, void* d_ws, size_t ws_size,
                              hipStream_t stream)
{
    const float* q      = (const float*)d_in[0];
    const float* k      = (const float*)d_in[1];
    const int*   labels = (const int*)d_in[2];
    float* out = (float*)d_out;
    float* ws  = (float*)d_ws;

    // zero the scalar-loss slot (harness poisons d_out before timed replays)
    hipMemsetAsync((char*)d_out + (size_t)B * S * sizeof(float), 0, sizeof(float), stream);

    pass1_kernel<<<dim3(B * TILES), dim3(256), 0, stream>>>(q, k, labels, ws);
    pass2_kernel<<<dim3(B, 2), dim3(512), 0, stream>>>(ws, out);
}